// Round 3
// baseline (490.311 us; speedup 1.0000x reference)
//
#include <hip/hip_runtime.h>

#define N_CH 128   // IN_CH == OUT_CH == 128
#define HCH  64    // hidden = OUT_CH/2

// ---------------- CSR build ----------------

__global__ void k_zero(int* __restrict__ cnt, int n) {
    int i = blockIdx.x * blockDim.x + threadIdx.x;
    if (i < n) cnt[i] = 0;
}

__global__ void k_count(const int* __restrict__ dst, int* __restrict__ cnt, int E) {
    int e = blockIdx.x * blockDim.x + threadIdx.x;
    if (e < E) atomicAdd(&cnt[dst[e]], 1);
}

// hierarchical scan, pass 1: per-block (1024) local exclusive scan + block total
__global__ __launch_bounds__(1024) void k_scan1(const int* __restrict__ cnt,
                                                int* __restrict__ offs,
                                                int* __restrict__ bsum, int n) {
    __shared__ int ssum[16];
    int tid = threadIdx.x;
    int lane = tid & 63, wid = tid >> 6;
    int i = blockIdx.x * 1024 + tid;
    int v = (i < n) ? cnt[i] : 0;
    int x = v;
    #pragma unroll
    for (int off = 1; off < 64; off <<= 1) {
        int y = __shfl_up(x, off, 64);
        if (lane >= off) x += y;
    }
    if (lane == 63) ssum[wid] = x;
    __syncthreads();
    if (wid == 0 && lane < 16) {
        int s = ssum[lane];
        #pragma unroll
        for (int off = 1; off < 16; off <<= 1) {
            int y = __shfl_up(s, off, 64);
            if (lane >= off) s += y;
        }
        ssum[lane] = s;
    }
    __syncthreads();
    int waveoff = (wid > 0) ? ssum[wid - 1] : 0;
    int incl = x + waveoff;
    if (i < n) offs[i] = incl - v;          // local exclusive
    if (tid == 1023) bsum[blockIdx.x] = incl;
}

// pass 2: scan block sums (nb <= 64) -> exclusive bases
__global__ __launch_bounds__(64) void k_scan2(const int* __restrict__ bsum,
                                              int* __restrict__ bbase, int nb) {
    int lane = threadIdx.x;
    int v = (lane < nb) ? bsum[lane] : 0;
    int x = v;
    #pragma unroll
    for (int off = 1; off < 64; off <<= 1) {
        int y = __shfl_up(x, off, 64);
        if (lane >= off) x += y;
    }
    if (lane < nb) bbase[lane] = x - v;
}

// pass 3: add base, replicate to cur, compute dinv
__global__ void k_scan3(const int* __restrict__ cnt, int* __restrict__ offs,
                        const int* __restrict__ bbase, int* __restrict__ cur,
                        float* __restrict__ dinv, int n) {
    int i = blockIdx.x * blockDim.x + threadIdx.x;
    if (i < n) {
        int o = offs[i] + bbase[i >> 10];
        offs[i] = o;
        cur[i]  = o;
        dinv[i] = rsqrtf((float)(cnt[i] + 1));   // deg includes self-loop
    }
}

// fill packed (src_index, src_weight) pairs
__global__ void k_fill(const int* __restrict__ src, const int* __restrict__ dst,
                       int* __restrict__ cur, const float* __restrict__ dinv,
                       int2* __restrict__ csr2, int E) {
    int e = blockIdx.x * blockDim.x + threadIdx.x;
    if (e < E) {
        int d = dst[e];
        int s = src[e];
        int p = atomicAdd(&cur[d], 1);
        int2 pk;
        pk.x = s;
        pk.y = __float_as_int(dinv[s]);
        csr2[p] = pk;
    }
}

// ---------------- one hop, XCD channel-sharded ----------------
// out[i] = dinv[i]*( dinv[i]*h[i] + sum_s dinv[s]*h[s] )
// slice = blockIdx % 8 (round-robin -> XCD); slice covers 16 channels,
// so each XCD's gather working set is 50000*16*4B = 3.2 MB < 4 MB L2.
// One wave per node: 4 neighbor subgroups x 16 channels, shuffle-reduce.

__global__ __launch_bounds__(256) void k_hop(const float* __restrict__ hin,
                                             float* __restrict__ hout,
                                             const int* __restrict__ offs,
                                             const int* __restrict__ cnt,
                                             const float* __restrict__ dinv,
                                             const int2* __restrict__ csr2, int n) {
    int slice = blockIdx.x & 7;
    int nbase = (blockIdx.x >> 3) * 16;
    int tid  = threadIdx.x;
    int lane = tid & 63, wid = tid >> 6;
    int sub = lane >> 4;                 // 0..3 neighbor subgroup
    int chg = slice * 16 + (lane & 15);  // global channel
    #pragma unroll
    for (int g = 0; g < 4; ++g) {
        int node = nbase + wid * 4 + g;
        if (node >= n) continue;
        int   s0 = offs[node];
        int   c  = cnt[node];
        float di = dinv[node];
        float self = hin[(size_t)node * N_CH + chg];
        const int2* lst = csr2 + s0;
        float acc = 0.0f;
        for (int t0 = 0; t0 < c; t0 += 8) {
            int ta = t0 + sub, tb = ta + 4;
            int2 ea = lst[ta < c ? ta : c - 1];
            int2 eb = lst[tb < c ? tb : c - 1];
            float ha = hin[(size_t)ea.x * N_CH + chg];
            float hb = hin[(size_t)eb.x * N_CH + chg];
            float wa = (ta < c) ? __int_as_float(ea.y) : 0.0f;
            float wb = (tb < c) ? __int_as_float(eb.y) : 0.0f;
            acc += wa * ha;
            acc += wb * hb;
        }
        acc += __shfl_xor(acc, 16, 64);
        acc += __shfl_xor(acc, 32, 64);
        if (sub == 0) hout[(size_t)node * N_CH + chg] = di * (acc + di * self);
    }
}

// ---------------- z = h @ W^T + b : tiled fp32 GEMM ----------------
// block tile: 64 nodes x 64 out-ch; 256 threads, 4x4 register tile each.

__global__ __launch_bounds__(256) void k_zlin(const float* __restrict__ h,
                                              const float* __restrict__ W,
                                              const float* __restrict__ b,
                                              float* __restrict__ z, int n) {
    __shared__ float hs[64 * 128];
    __shared__ float ws[64 * 128];
    int tid = threadIdx.x;
    int nb = (blockIdx.x >> 1) * 64;   // node base
    int cb = (blockIdx.x & 1) * 64;    // out-channel base
    #pragma unroll
    for (int i = 0; i < 8; ++i) {       // stage h tile
        int g = tid + 256 * i;
        int r = g >> 5, c = g & 31;
        float4 vv = ((const float4*)(h + (size_t)(nb + r) * N_CH))[c];
        ((float4*)hs)[r * 32 + (c ^ (r & 31))] = vv;
    }
    #pragma unroll
    for (int i = 0; i < 8; ++i) {       // stage W half-tile
        int g = tid + 256 * i;
        int r = g >> 5, c = g & 31;
        float4 vv = ((const float4*)(W + (size_t)(cb + r) * N_CH))[c];
        ((float4*)ws)[r * 32 + (c ^ (r & 31))] = vv;
    }
    __syncthreads();
    int pc = tid & 15, hr = tid >> 4;
    int h0 = hr * 4;
    float acc[4][4];
    #pragma unroll
    for (int i = 0; i < 4; ++i)
        #pragma unroll
        for (int j = 0; j < 4; ++j) acc[i][j] = 0.0f;
    #pragma unroll 4
    for (int kc = 0; kc < 32; ++kc) {
        float4 sv[4], wv[4];
        #pragma unroll
        for (int i = 0; i < 4; ++i) {
            int p = pc + 16 * i;
            sv[i] = ((const float4*)hs)[p * 32 + (kc ^ (p & 31))];
        }
        #pragma unroll
        for (int j = 0; j < 4; ++j) {
            int hh = h0 + j;
            wv[j] = ((const float4*)ws)[hh * 32 + (kc ^ (hh & 31))];
        }
        #pragma unroll
        for (int i = 0; i < 4; ++i)
            #pragma unroll
            for (int j = 0; j < 4; ++j)
                acc[i][j] += sv[i].x * wv[j].x + sv[i].y * wv[j].y +
                             sv[i].z * wv[j].z + sv[i].w * wv[j].w;
    }
    float4 bv = *(const float4*)(b + cb + h0);
    float bb[4] = {bv.x, bv.y, bv.z, bv.w};
    #pragma unroll
    for (int i = 0; i < 4; ++i) {
        int node = nb + pc + 16 * i;
        if (node < n) {
            float4 o;
            o.x = acc[i][0] + bb[0];
            o.y = acc[i][1] + bb[1];
            o.z = acc[i][2] + bb[2];
            o.w = acc[i][3] + bb[3];
            *(float4*)(z + (size_t)node * N_CH + cb + h0) = o;
        }
    }
}

// ---------------- decode: K-split tiled GEMM, 64 pairs/block ----------------
// LDS halved to 32 KB (16 KB s-tile + 16 KB W1-tile per K-half) -> 4 blocks/CU.

__global__ __launch_bounds__(256) void k_decode(const float* __restrict__ z,
                                                const int* __restrict__ ai,
                                                const int* __restrict__ bi,
                                                const float* __restrict__ W1,
                                                const float* __restrict__ b1,
                                                const float* __restrict__ w2,
                                                const float* __restrict__ b2,
                                                float* __restrict__ out, int m) {
    __shared__ float s_s[64 * 64];   // 16 KB; epilogue reuses with stride 17
    __shared__ float w1s[64 * 64];   // 16 KB
    int tid = threadIdx.x;
    int lane = tid & 63, wid = tid >> 6;
    int pbase = blockIdx.x * 64;
    int pc = tid & 15, hr = tid >> 4;
    int h0 = hr * 4;

    float4 b1v = *(const float4*)(b1 + h0);
    float acc[4][4];
    #pragma unroll
    for (int i = 0; i < 4; ++i) {
        acc[i][0] = b1v.x; acc[i][1] = b1v.y; acc[i][2] = b1v.z; acc[i][3] = b1v.w;
    }

    #pragma unroll
    for (int half = 0; half < 2; ++half) {
        if (half) __syncthreads();   // all waves done reading previous tiles
        // stage W1 half: rows 0..63, k in [half*64, half*64+64)
        #pragma unroll
        for (int i = 0; i < 4; ++i) {
            int g = tid + 256 * i;       // 0..1023
            int r = g >> 4, c = g & 15;
            float4 vv = *(const float4*)(W1 + (size_t)r * N_CH + half * 64 + c * 4);
            ((float4*)w1s)[r * 16 + (c ^ (r & 15))] = vv;
        }
        // stage s half: wave wid owns pairs wid*16..+15; whole wave per pair
        int pb = wid * 16;
        #pragma unroll 4
        for (int it = 0; it < 16; ++it) {
            int p = pb + it;
            int gp = pbase + p; gp = (gp < m) ? gp : (m - 1);
            int ia = ai[gp], ib = bi[gp];
            float a = z[(size_t)ia * N_CH + half * 64 + lane];
            float bq = z[(size_t)ib * N_CH + half * 64 + lane];
            s_s[p * 64 + ((((lane >> 2) ^ (p & 15))) << 2) + (lane & 3)] = a * bq;
        }
        __syncthreads();
        // GEMM over this K-half: 16 float4 k-chunks
        #pragma unroll 4
        for (int kc = 0; kc < 16; ++kc) {
            float4 sv[4], wv[4];
            #pragma unroll
            for (int i = 0; i < 4; ++i) {
                int p = pc + 16 * i;
                sv[i] = ((const float4*)s_s)[p * 16 + (kc ^ (p & 15))];
            }
            #pragma unroll
            for (int j = 0; j < 4; ++j) {
                int hh = h0 + j;
                wv[j] = ((const float4*)w1s)[hh * 16 + (kc ^ (hh & 15))];
            }
            #pragma unroll
            for (int i = 0; i < 4; ++i)
                #pragma unroll
                for (int j = 0; j < 4; ++j)
                    acc[i][j] += sv[i].x * wv[j].x + sv[i].y * wv[j].y +
                                 sv[i].z * wv[j].z + sv[i].w * wv[j].w;
        }
    }
    __syncthreads();
    // epilogue: relu, *w2, partial-reduce via padded LDS (stride 17)
    float4 w2v = *(const float4*)(w2 + h0);
    float w2a[4] = {w2v.x, w2v.y, w2v.z, w2v.w};
    #pragma unroll
    for (int i = 0; i < 4; ++i) {
        int p = pc + 16 * i;
        float pr = 0.0f;
        #pragma unroll
        for (int j = 0; j < 4; ++j) pr += w2a[j] * fmaxf(acc[i][j], 0.0f);
        s_s[p * 17 + hr] = pr;
    }
    __syncthreads();
    if (tid < 64) {
        float r = b2[0];
        #pragma unroll
        for (int j = 0; j < 16; ++j) r += s_s[tid * 17 + j];
        int gp = pbase + tid;
        if (gp < m) out[gp] = r;
    }
}

// ---------------- launch ----------------

extern "C" void kernel_launch(void* const* d_in, const int* in_sizes, int n_in,
                              void* d_out, int out_size, void* d_ws, size_t ws_size,
                              hipStream_t stream) {
    const float* x   = (const float*)d_in[0];
    const int*   ei  = (const int*)d_in[1];
    const int*   eli = (const int*)d_in[2];
    const float* W   = (const float*)d_in[3];
    const float* bc  = (const float*)d_in[4];
    const float* W1  = (const float*)d_in[5];
    const float* b1  = (const float*)d_in[6];
    const float* w2  = (const float*)d_in[7];
    const float* b2  = (const float*)d_in[8];
    float* out = (float*)d_out;

    const int N = in_sizes[0] / N_CH;   // 50000
    const int E = in_sizes[1] / 2;      // 600000
    const int M = in_sizes[2] / 2;      // 200000

    const int* src = ei;
    const int* dst = ei + E;
    const int* ai  = eli;
    const int* bi  = eli + M;

    // workspace layout
    float* hA   = (float*)d_ws;                    // N*128
    float* hB   = hA + (size_t)N * N_CH;           // N*128
    int2*  csr2 = (int2*)(hB + (size_t)N * N_CH);  // E int2
    int*   cnt  = (int*)(csr2 + E);                // N
    int*   off  = cnt + N;                         // N
    int*   cur  = off + N;                         // N
    float* dnv  = (float*)(cur + N);               // N
    int*   bsum = (int*)(dnv + N);                 // 64
    int*   bbas = bsum + 64;                       // 64

    // 1) CSR by dst (with packed per-edge weights); hierarchical scan
    int nb = (N + 1023) / 1024;
    k_zero<<<(N + 255) / 256, 256, 0, stream>>>(cnt, N);
    k_count<<<(E + 255) / 256, 256, 0, stream>>>(dst, cnt, E);
    k_scan1<<<nb, 1024, 0, stream>>>(cnt, off, bsum, N);
    k_scan2<<<1, 64, 0, stream>>>(bsum, bbas, nb);
    k_scan3<<<(N + 255) / 256, 256, 0, stream>>>(cnt, off, bbas, cur, dnv, N);
    k_fill<<<(E + 255) / 256, 256, 0, stream>>>(src, dst, cur, dnv, csr2, E);

    // 2) two propagation hops, XCD channel-sharded (8 slices x 16 nodes/block)
    int hop_blocks = 8 * ((N + 15) / 16);
    k_hop<<<hop_blocks, 256, 0, stream>>>(x,  hA, off, cnt, dnv, csr2, N);
    k_hop<<<hop_blocks, 256, 0, stream>>>(hA, hB, off, cnt, dnv, csr2, N);

    // 3) z = hB @ W^T + bc  (into hA)
    int ntiles = (N + 63) / 64;
    k_zlin<<<ntiles * 2, 256, 0, stream>>>(hB, W, bc, hA, N);

    // 4) decode (K-split tiled GEMM, 64 pairs per block)
    k_decode<<<(M + 63) / 64, 256, 0, stream>>>(hA, ai, bi, W1, b1, w2, b2, out, M);
}

// Round 4
// 353.976 us; speedup vs baseline: 1.3852x; 1.3852x over previous
//
#include <hip/hip_runtime.h>

#define N_CH 128   // IN_CH == OUT_CH == 128
#define HCH  64    // hidden = OUT_CH/2

// ---------------- CSR build ----------------

__global__ void k_zero(int* __restrict__ cnt, int n) {
    int i = blockIdx.x * blockDim.x + threadIdx.x;
    if (i < n) cnt[i] = 0;
}

__global__ void k_count(const int* __restrict__ dst, int* __restrict__ cnt, int E) {
    int e = blockIdx.x * blockDim.x + threadIdx.x;
    if (e < E) atomicAdd(&cnt[dst[e]], 1);
}

// hierarchical scan, pass 1: per-block (1024) local exclusive scan + block total
__global__ __launch_bounds__(1024) void k_scan1(const int* __restrict__ cnt,
                                                int* __restrict__ offs,
                                                int* __restrict__ bsum, int n) {
    __shared__ int ssum[16];
    int tid = threadIdx.x;
    int lane = tid & 63, wid = tid >> 6;
    int i = blockIdx.x * 1024 + tid;
    int v = (i < n) ? cnt[i] : 0;
    int x = v;
    #pragma unroll
    for (int off = 1; off < 64; off <<= 1) {
        int y = __shfl_up(x, off, 64);
        if (lane >= off) x += y;
    }
    if (lane == 63) ssum[wid] = x;
    __syncthreads();
    if (wid == 0 && lane < 16) {
        int s = ssum[lane];
        #pragma unroll
        for (int off = 1; off < 16; off <<= 1) {
            int y = __shfl_up(s, off, 64);
            if (lane >= off) s += y;
        }
        ssum[lane] = s;
    }
    __syncthreads();
    int waveoff = (wid > 0) ? ssum[wid - 1] : 0;
    int incl = x + waveoff;
    if (i < n) offs[i] = incl - v;          // local exclusive
    if (tid == 1023) bsum[blockIdx.x] = incl;
}

// pass 2: scan block sums (nb <= 64) -> exclusive bases
__global__ __launch_bounds__(64) void k_scan2(const int* __restrict__ bsum,
                                              int* __restrict__ bbase, int nb) {
    int lane = threadIdx.x;
    int v = (lane < nb) ? bsum[lane] : 0;
    int x = v;
    #pragma unroll
    for (int off = 1; off < 64; off <<= 1) {
        int y = __shfl_up(x, off, 64);
        if (lane >= off) x += y;
    }
    if (lane < nb) bbase[lane] = x - v;
}

// pass 3: add base, replicate to cur, compute dinv
__global__ void k_scan3(const int* __restrict__ cnt, int* __restrict__ offs,
                        const int* __restrict__ bbase, int* __restrict__ cur,
                        float* __restrict__ dinv, int n) {
    int i = blockIdx.x * blockDim.x + threadIdx.x;
    if (i < n) {
        int o = offs[i] + bbase[i >> 10];
        offs[i] = o;
        cur[i]  = o;
        dinv[i] = rsqrtf((float)(cnt[i] + 1));   // deg includes self-loop
    }
}

// fill packed (src_index, src_weight) pairs
__global__ void k_fill(const int* __restrict__ src, const int* __restrict__ dst,
                       int* __restrict__ cur, const float* __restrict__ dinv,
                       int2* __restrict__ csr2, int E) {
    int e = blockIdx.x * blockDim.x + threadIdx.x;
    if (e < E) {
        int d = dst[e];
        int s = src[e];
        int p = atomicAdd(&cur[d], 1);
        int2 pk;
        pk.x = s;
        pk.y = __float_as_int(dinv[s]);
        csr2[p] = pk;
    }
}

// ---------------- one hop: whole-row float4 gathers, 16 rows in flight ----------------
// out[i] = dinv[i]*( dinv[i]*h[i] + sum_s dinv[s]*h[s] )
// wave = node; lane reads float4: 32 lanes = one 512B row, the wave's two
// halves handle even/odd neighbors -> each load instr fetches 2 full rows.
// 8 loads batched per iteration = 16 neighbor rows (8 KB) in flight per wave.

__global__ __launch_bounds__(256) void k_hop(const float* __restrict__ hin,
                                             float* __restrict__ hout,
                                             const int* __restrict__ offs,
                                             const int* __restrict__ cnt,
                                             const float* __restrict__ dinv,
                                             const int2* __restrict__ csr2, int n) {
    int node = blockIdx.x * 4 + (threadIdx.x >> 6);
    int lane = threadIdx.x & 63;
    if (node >= n) return;
    int half = lane >> 5;       // 0: even-index neighbors, 1: odd
    int cq   = lane & 31;       // float4 chunk within row
    float di = dinv[node];
    float4 self = ((const float4*)(hin + (size_t)node * N_CH))[cq];
    float4 acc;
    if (half == 0) { acc.x = di * self.x; acc.y = di * self.y; acc.z = di * self.z; acc.w = di * self.w; }
    else           { acc.x = 0.f; acc.y = 0.f; acc.z = 0.f; acc.w = 0.f; }
    int s0 = offs[node];
    int c  = cnt[node];
    const int2* lst = csr2 + s0;
    for (int t0 = 0; t0 < c; t0 += 16) {
        int2 e[8];
        #pragma unroll
        for (int i = 0; i < 8; ++i) {
            int tt = t0 + 2 * i + half;
            if (tt < c) e[i] = lst[tt];
            else { e[i].x = node; e[i].y = 0; }   // self row (L1-hot), weight 0
        }
        float4 u[8];
        #pragma unroll
        for (int i = 0; i < 8; ++i)
            u[i] = ((const float4*)(hin + (size_t)e[i].x * N_CH))[cq];
        #pragma unroll
        for (int i = 0; i < 8; ++i) {
            float wg = __int_as_float(e[i].y);
            acc.x += wg * u[i].x;
            acc.y += wg * u[i].y;
            acc.z += wg * u[i].z;
            acc.w += wg * u[i].w;
        }
    }
    // combine even/odd halves (lane ^ 32 holds the other partial)
    acc.x += __shfl_xor(acc.x, 32, 64);
    acc.y += __shfl_xor(acc.y, 32, 64);
    acc.z += __shfl_xor(acc.z, 32, 64);
    acc.w += __shfl_xor(acc.w, 32, 64);
    if (half == 0) {
        float4 o;
        o.x = di * acc.x; o.y = di * acc.y; o.z = di * acc.z; o.w = di * acc.w;
        ((float4*)(hout + (size_t)node * N_CH))[cq] = o;
    }
}

// ---------------- z = h @ W^T + b : tiled fp32 GEMM ----------------
// block tile: 64 nodes x 64 out-ch; 256 threads, 4x4 register tile each.

__global__ __launch_bounds__(256) void k_zlin(const float* __restrict__ h,
                                              const float* __restrict__ W,
                                              const float* __restrict__ b,
                                              float* __restrict__ z, int n) {
    __shared__ float hs[64 * 128];
    __shared__ float ws[64 * 128];
    int tid = threadIdx.x;
    int nb = (blockIdx.x >> 1) * 64;   // node base
    int cb = (blockIdx.x & 1) * 64;    // out-channel base
    #pragma unroll
    for (int i = 0; i < 8; ++i) {       // stage h tile
        int g = tid + 256 * i;
        int r = g >> 5, c = g & 31;
        float4 vv = ((const float4*)(h + (size_t)(nb + r) * N_CH))[c];
        ((float4*)hs)[r * 32 + (c ^ (r & 31))] = vv;
    }
    #pragma unroll
    for (int i = 0; i < 8; ++i) {       // stage W half-tile
        int g = tid + 256 * i;
        int r = g >> 5, c = g & 31;
        float4 vv = ((const float4*)(W + (size_t)(cb + r) * N_CH))[c];
        ((float4*)ws)[r * 32 + (c ^ (r & 31))] = vv;
    }
    __syncthreads();
    int pc = tid & 15, hr = tid >> 4;
    int h0 = hr * 4;
    float acc[4][4];
    #pragma unroll
    for (int i = 0; i < 4; ++i)
        #pragma unroll
        for (int j = 0; j < 4; ++j) acc[i][j] = 0.0f;
    #pragma unroll 4
    for (int kc = 0; kc < 32; ++kc) {
        float4 sv[4], wv[4];
        #pragma unroll
        for (int i = 0; i < 4; ++i) {
            int p = pc + 16 * i;
            sv[i] = ((const float4*)hs)[p * 32 + (kc ^ (p & 31))];
        }
        #pragma unroll
        for (int j = 0; j < 4; ++j) {
            int hh = h0 + j;
            wv[j] = ((const float4*)ws)[hh * 32 + (kc ^ (hh & 31))];
        }
        #pragma unroll
        for (int i = 0; i < 4; ++i)
            #pragma unroll
            for (int j = 0; j < 4; ++j)
                acc[i][j] += sv[i].x * wv[j].x + sv[i].y * wv[j].y +
                             sv[i].z * wv[j].z + sv[i].w * wv[j].w;
    }
    float4 bv = *(const float4*)(b + cb + h0);
    float bb[4] = {bv.x, bv.y, bv.z, bv.w};
    #pragma unroll
    for (int i = 0; i < 4; ++i) {
        int node = nb + pc + 16 * i;
        if (node < n) {
            float4 o;
            o.x = acc[i][0] + bb[0];
            o.y = acc[i][1] + bb[1];
            o.z = acc[i][2] + bb[2];
            o.w = acc[i][3] + bb[3];
            *(float4*)(z + (size_t)node * N_CH + cb + h0) = o;
        }
    }
}

// ---------------- decode: K-split tiled GEMM, 64 pairs/block ----------------
// LDS 32 KB (16 KB s-tile + 16 KB W1-tile per K-half) -> 4 blocks/CU.

__global__ __launch_bounds__(256) void k_decode(const float* __restrict__ z,
                                                const int* __restrict__ ai,
                                                const int* __restrict__ bi,
                                                const float* __restrict__ W1,
                                                const float* __restrict__ b1,
                                                const float* __restrict__ w2,
                                                const float* __restrict__ b2,
                                                float* __restrict__ out, int m) {
    __shared__ float s_s[64 * 64];   // 16 KB; epilogue reuses with stride 17
    __shared__ float w1s[64 * 64];   // 16 KB
    int tid = threadIdx.x;
    int lane = tid & 63, wid = tid >> 6;
    int pbase = blockIdx.x * 64;
    int pc = tid & 15, hr = tid >> 4;
    int h0 = hr * 4;

    float4 b1v = *(const float4*)(b1 + h0);
    float acc[4][4];
    #pragma unroll
    for (int i = 0; i < 4; ++i) {
        acc[i][0] = b1v.x; acc[i][1] = b1v.y; acc[i][2] = b1v.z; acc[i][3] = b1v.w;
    }

    #pragma unroll
    for (int half = 0; half < 2; ++half) {
        if (half) __syncthreads();   // all waves done reading previous tiles
        // stage W1 half: rows 0..63, k in [half*64, half*64+64)
        #pragma unroll
        for (int i = 0; i < 4; ++i) {
            int g = tid + 256 * i;       // 0..1023
            int r = g >> 4, c = g & 15;
            float4 vv = *(const float4*)(W1 + (size_t)r * N_CH + half * 64 + c * 4);
            ((float4*)w1s)[r * 16 + (c ^ (r & 15))] = vv;
        }
        // stage s half: wave wid owns pairs wid*16..+15; whole wave per pair
        int pb = wid * 16;
        #pragma unroll 4
        for (int it = 0; it < 16; ++it) {
            int p = pb + it;
            int gp = pbase + p; gp = (gp < m) ? gp : (m - 1);
            int ia = ai[gp], ib = bi[gp];
            float a = z[(size_t)ia * N_CH + half * 64 + lane];
            float bq = z[(size_t)ib * N_CH + half * 64 + lane];
            s_s[p * 64 + ((((lane >> 2) ^ (p & 15))) << 2) + (lane & 3)] = a * bq;
        }
        __syncthreads();
        // GEMM over this K-half: 16 float4 k-chunks
        #pragma unroll 4
        for (int kc = 0; kc < 16; ++kc) {
            float4 sv[4], wv[4];
            #pragma unroll
            for (int i = 0; i < 4; ++i) {
                int p = pc + 16 * i;
                sv[i] = ((const float4*)s_s)[p * 16 + (kc ^ (p & 15))];
            }
            #pragma unroll
            for (int j = 0; j < 4; ++j) {
                int hh = h0 + j;
                wv[j] = ((const float4*)w1s)[hh * 16 + (kc ^ (hh & 15))];
            }
            #pragma unroll
            for (int i = 0; i < 4; ++i)
                #pragma unroll
                for (int j = 0; j < 4; ++j)
                    acc[i][j] += sv[i].x * wv[j].x + sv[i].y * wv[j].y +
                                 sv[i].z * wv[j].z + sv[i].w * wv[j].w;
        }
    }
    __syncthreads();
    // epilogue: relu, *w2, partial-reduce via padded LDS (stride 17)
    float4 w2v = *(const float4*)(w2 + h0);
    float w2a[4] = {w2v.x, w2v.y, w2v.z, w2v.w};
    #pragma unroll
    for (int i = 0; i < 4; ++i) {
        int p = pc + 16 * i;
        float pr = 0.0f;
        #pragma unroll
        for (int j = 0; j < 4; ++j) pr += w2a[j] * fmaxf(acc[i][j], 0.0f);
        s_s[p * 17 + hr] = pr;
    }
    __syncthreads();
    if (tid < 64) {
        float r = b2[0];
        #pragma unroll
        for (int j = 0; j < 16; ++j) r += s_s[tid * 17 + j];
        int gp = pbase + tid;
        if (gp < m) out[gp] = r;
    }
}

// ---------------- launch ----------------

extern "C" void kernel_launch(void* const* d_in, const int* in_sizes, int n_in,
                              void* d_out, int out_size, void* d_ws, size_t ws_size,
                              hipStream_t stream) {
    const float* x   = (const float*)d_in[0];
    const int*   ei  = (const int*)d_in[1];
    const int*   eli = (const int*)d_in[2];
    const float* W   = (const float*)d_in[3];
    const float* bc  = (const float*)d_in[4];
    const float* W1  = (const float*)d_in[5];
    const float* b1  = (const float*)d_in[6];
    const float* w2  = (const float*)d_in[7];
    const float* b2  = (const float*)d_in[8];
    float* out = (float*)d_out;

    const int N = in_sizes[0] / N_CH;   // 50000
    const int E = in_sizes[1] / 2;      // 600000
    const int M = in_sizes[2] / 2;      // 200000

    const int* src = ei;
    const int* dst = ei + E;
    const int* ai  = eli;
    const int* bi  = eli + M;

    // workspace layout
    float* hA   = (float*)d_ws;                    // N*128
    float* hB   = hA + (size_t)N * N_CH;           // N*128
    int2*  csr2 = (int2*)(hB + (size_t)N * N_CH);  // E int2
    int*   cnt  = (int*)(csr2 + E);                // N
    int*   off  = cnt + N;                         // N
    int*   cur  = off + N;                         // N
    float* dnv  = (float*)(cur + N);               // N
    int*   bsum = (int*)(dnv + N);                 // 64
    int*   bbas = bsum + 64;                       // 64

    // 1) CSR by dst (with packed per-edge weights); hierarchical scan
    int nb = (N + 1023) / 1024;
    k_zero<<<(N + 255) / 256, 256, 0, stream>>>(cnt, N);
    k_count<<<(E + 255) / 256, 256, 0, stream>>>(dst, cnt, E);
    k_scan1<<<nb, 1024, 0, stream>>>(cnt, off, bsum, N);
    k_scan2<<<1, 64, 0, stream>>>(bsum, bbas, nb);
    k_scan3<<<(N + 255) / 256, 256, 0, stream>>>(cnt, off, bbas, cur, dnv, N);
    k_fill<<<(E + 255) / 256, 256, 0, stream>>>(src, dst, cur, dnv, csr2, E);

    // 2) two propagation hops (wave per node, whole-row float4 gathers)
    int hop_blocks = (N + 3) / 4;
    k_hop<<<hop_blocks, 256, 0, stream>>>(x,  hA, off, cnt, dnv, csr2, N);
    k_hop<<<hop_blocks, 256, 0, stream>>>(hA, hB, off, cnt, dnv, csr2, N);

    // 3) z = hB @ W^T + bc  (into hA)
    int ntiles = (N + 63) / 64;
    k_zlin<<<ntiles * 2, 256, 0, stream>>>(hB, W, bc, hA, N);

    // 4) decode (K-split tiled GEMM, 64 pairs per block)
    k_decode<<<(M + 63) / 64, 256, 0, stream>>>(hA, ai, bi, W1, b1, w2, b2, out, M);
}

// Round 5
// 255.285 us; speedup vs baseline: 1.9206x; 1.3866x over previous
//
#include <hip/hip_runtime.h>

#define N_CH 128   // IN_CH == OUT_CH == 128

typedef _Float16 half8  __attribute__((ext_vector_type(8)));
typedef _Float16 half4v __attribute__((ext_vector_type(4)));
typedef _Float16 half2v __attribute__((ext_vector_type(2)));
typedef float    floatx4 __attribute__((ext_vector_type(4)));

// ---------------- CSR build ----------------

__global__ void k_zero(int* __restrict__ cnt, int n) {
    int i = blockIdx.x * blockDim.x + threadIdx.x;
    if (i < n) cnt[i] = 0;
}

__global__ void k_count(const int* __restrict__ dst, int* __restrict__ cnt, int E) {
    int e = blockIdx.x * blockDim.x + threadIdx.x;
    if (e < E) atomicAdd(&cnt[dst[e]], 1);
}

// hierarchical scan, pass 1: per-block (1024) local exclusive scan + block total
__global__ __launch_bounds__(1024) void k_scan1(const int* __restrict__ cnt,
                                                int* __restrict__ offs,
                                                int* __restrict__ bsum, int n) {
    __shared__ int ssum[16];
    int tid = threadIdx.x;
    int lane = tid & 63, wid = tid >> 6;
    int i = blockIdx.x * 1024 + tid;
    int v = (i < n) ? cnt[i] : 0;
    int x = v;
    #pragma unroll
    for (int off = 1; off < 64; off <<= 1) {
        int y = __shfl_up(x, off, 64);
        if (lane >= off) x += y;
    }
    if (lane == 63) ssum[wid] = x;
    __syncthreads();
    if (wid == 0 && lane < 16) {
        int s = ssum[lane];
        #pragma unroll
        for (int off = 1; off < 16; off <<= 1) {
            int y = __shfl_up(s, off, 64);
            if (lane >= off) s += y;
        }
        ssum[lane] = s;
    }
    __syncthreads();
    int waveoff = (wid > 0) ? ssum[wid - 1] : 0;
    int incl = x + waveoff;
    if (i < n) offs[i] = incl - v;          // local exclusive
    if (tid == 1023) bsum[blockIdx.x] = incl;
}

// pass 2: scan block sums (nb <= 64) -> exclusive bases
__global__ __launch_bounds__(64) void k_scan2(const int* __restrict__ bsum,
                                              int* __restrict__ bbase, int nb) {
    int lane = threadIdx.x;
    int v = (lane < nb) ? bsum[lane] : 0;
    int x = v;
    #pragma unroll
    for (int off = 1; off < 64; off <<= 1) {
        int y = __shfl_up(x, off, 64);
        if (lane >= off) x += y;
    }
    if (lane < nb) bbase[lane] = x - v;
}

// pass 3: add base, replicate to cur, compute dinv
__global__ void k_scan3(const int* __restrict__ cnt, int* __restrict__ offs,
                        const int* __restrict__ bbase, int* __restrict__ cur,
                        float* __restrict__ dinv, int n) {
    int i = blockIdx.x * blockDim.x + threadIdx.x;
    if (i < n) {
        int o = offs[i] + bbase[i >> 10];
        offs[i] = o;
        cur[i]  = o;
        dinv[i] = rsqrtf((float)(cnt[i] + 1));   // deg includes self-loop
    }
}

// fill packed (src_index, src_weight) pairs
__global__ void k_fill(const int* __restrict__ src, const int* __restrict__ dst,
                       int* __restrict__ cur, const float* __restrict__ dinv,
                       int2* __restrict__ csr2, int E) {
    int e = blockIdx.x * blockDim.x + threadIdx.x;
    if (e < E) {
        int d = dst[e];
        int s = src[e];
        int p = atomicAdd(&cur[d], 1);
        int2 pk;
        pk.x = s;
        pk.y = __float_as_int(dinv[s]);
        csr2[p] = pk;
    }
}

// ---------------- fp32 -> fp16 conversion of x, W, W1 (float4 granules) ----------------

__global__ void k_cvt(const float* __restrict__ x,  _Float16* __restrict__ xh,  int nx4,
                      const float* __restrict__ W,  _Float16* __restrict__ wh,  int nw4,
                      const float* __restrict__ W1, _Float16* __restrict__ w1h, int nw14) {
    int i = blockIdx.x * blockDim.x + threadIdx.x;
    const float4* s; half4v* d; int j;
    if (i < nx4)                { s = (const float4*)x;  d = (half4v*)xh;  j = i; }
    else if (i < nx4 + nw4)     { s = (const float4*)W;  d = (half4v*)wh;  j = i - nx4; }
    else if (i < nx4 + nw4 + nw14) { s = (const float4*)W1; d = (half4v*)w1h; j = i - nx4 - nw4; }
    else return;
    float4 v = s[j];
    half4v o;
    o[0] = (_Float16)v.x; o[1] = (_Float16)v.y; o[2] = (_Float16)v.z; o[3] = (_Float16)v.w;
    d[j] = o;
}

// ---------------- one hop, fp16 rows, fp32 accumulate ----------------
// out[i] = dinv[i]*( dinv[i]*h[i] + sum_s dinv[s]*h[s] )
// wave = node; row = 128 halves = 16 chunks of 16B; lane&15 = chunk,
// lane>>4 = neighbor subgroup. One wave-load covers 4 rows; 4 batched
// loads = 16 neighbor rows (4 KB) in flight per wave.

__global__ __launch_bounds__(256) void k_hop16(const _Float16* __restrict__ hin,
                                               _Float16* __restrict__ hout,
                                               const int* __restrict__ offs,
                                               const int* __restrict__ cnt,
                                               const float* __restrict__ dinv,
                                               const int2* __restrict__ csr2, int n) {
    int node = blockIdx.x * 4 + (threadIdx.x >> 6);
    int lane = threadIdx.x & 63;
    if (node >= n) return;
    int chunk = lane & 15, sub = lane >> 4;
    float di = dinv[node];
    half8 self = ((const half8*)(hin + (size_t)node * N_CH))[chunk];
    float acc[8];
    #pragma unroll
    for (int j = 0; j < 8; ++j) acc[j] = (sub == 0) ? di * (float)self[j] : 0.0f;
    int s0 = offs[node], c = cnt[node];
    const int2* lst = csr2 + s0;
    for (int t0 = 0; t0 < c; t0 += 16) {
        int2 e[4];
        #pragma unroll
        for (int i = 0; i < 4; ++i) {
            int t = t0 + i * 4 + sub;
            if (t < c) e[i] = lst[t];
            else { e[i].x = node; e[i].y = 0; }   // self row (L1-hot), weight 0
        }
        half8 u[4];
        #pragma unroll
        for (int i = 0; i < 4; ++i)
            u[i] = ((const half8*)(hin + (size_t)e[i].x * N_CH))[chunk];
        #pragma unroll
        for (int i = 0; i < 4; ++i) {
            float wg = __int_as_float(e[i].y);
            #pragma unroll
            for (int j = 0; j < 8; ++j) acc[j] += wg * (float)u[i][j];
        }
    }
    #pragma unroll
    for (int j = 0; j < 8; ++j) {
        acc[j] += __shfl_xor(acc[j], 16, 64);
        acc[j] += __shfl_xor(acc[j], 32, 64);
    }
    if (sub == 0) {
        half8 o;
        #pragma unroll
        for (int j = 0; j < 8; ++j) o[j] = (_Float16)(di * acc[j]);
        ((half8*)(hout + (size_t)node * N_CH))[chunk] = o;
    }
}

// ---------------- z = h @ W^T + b : fp16 MFMA GEMM ----------------
// block = 4 waves, tile 64 nodes x 128 out-ch. W (128x128 fp16) in swizzled
// LDS; A-frags straight from global fp16 h. mfma_f32_16x16x32_f16:
// A[m=lane&15][k=quad*8+j], B[n=lane&15][k=quad*8+j], D: col=lane&15,
// row=quad*4+reg (HW-verified layouts, m89/m120).

__global__ __launch_bounds__(256) void k_zlin_mfma(const _Float16* __restrict__ h,
                                                   const _Float16* __restrict__ wh,
                                                   const float* __restrict__ bc,
                                                   _Float16* __restrict__ z, int n) {
    __shared__ half8 wls[128 * 16];   // row r chunk c at r*16 + (c^(r&15))
    int tid = threadIdx.x;
    int lane = tid & 63, w = tid >> 6;
    int quad = lane >> 4, m16 = lane & 15;
    int nb = blockIdx.x * 64;
    #pragma unroll
    for (int i = 0; i < 8; ++i) {
        int g = tid + 256 * i;   // 0..2047 chunk id = r*16 + c
        int r = g >> 4, c = g & 15;
        wls[r * 16 + (c ^ (r & 15))] = ((const half8*)wh)[g];
    }
    // preload A-frags: node row = nb + w*16 + m16, chunk = kk*4 + quad
    int arow = nb + w * 16 + m16;      // may run past n; stays inside d_ws
    const half8* hrow = (const half8*)(h + (size_t)arow * N_CH);
    half8 a[4];
    #pragma unroll
    for (int kk = 0; kk < 4; ++kk) a[kk] = hrow[kk * 4 + quad];
    __syncthreads();
    int outnode0 = nb + w * 16 + quad * 4;
    #pragma unroll
    for (int jt = 0; jt < 8; ++jt) {
        floatx4 acc = {0.f, 0.f, 0.f, 0.f};
        #pragma unroll
        for (int kk = 0; kk < 4; ++kk) {
            int r = jt * 16 + m16;
            half8 bfr = wls[r * 16 + ((kk * 4 + quad) ^ m16)];
            acc = __builtin_amdgcn_mfma_f32_16x16x32_f16(a[kk], bfr, acc, 0, 0, 0);
        }
        int j = jt * 16 + m16;
        float bias = bc[j];
        #pragma unroll
        for (int reg = 0; reg < 4; ++reg) {
            int node = outnode0 + reg;
            if (node < n) z[(size_t)node * N_CH + j] = (_Float16)(acc[reg] + bias);
        }
    }
}

// ---------------- decode: fp16 MFMA, 64 pairs x 64 hidden per block ----------------
// s = z[a]*z[b] staged per-wave to swizzled LDS fp16; W1 LDS-resident;
// epilogue: +b1, relu, *w2, shuffle-reduce over hidden, +b2.

__global__ __launch_bounds__(256) void k_decode_mfma(const _Float16* __restrict__ z,
        const int* __restrict__ ai, const int* __restrict__ bi,
        const _Float16* __restrict__ w1h, const float* __restrict__ b1,
        const float* __restrict__ w2, const float* __restrict__ b2,
        float* __restrict__ out, int m) {
    __shared__ half8 w1ls[64 * 16];
    __shared__ half8 sls[64 * 16];
    int tid = threadIdx.x;
    int lane = tid & 63, w = tid >> 6;
    int quad = lane >> 4, m16 = lane & 15;
    int pbase = blockIdx.x * 64;
    #pragma unroll
    for (int i = 0; i < 4; ++i) {
        int g = tid + 256 * i;   // 0..1023
        int r = g >> 4, c = g & 15;
        w1ls[r * 16 + (c ^ (r & 15))] = ((const half8*)w1h)[g];
    }
    // pair indices for this wave's 16 pairs, broadcast via shfl
    int pidx = pbase + w * 16 + m16;
    if (pidx >= m) pidx = m - 1;
    int idxa = ai[pidx];
    int idxb = bi[pidx];
    half2v* sls2 = (half2v*)sls;     // row p = 64 half2v words
    #pragma unroll 2
    for (int it = 0; it < 16; ++it) {
        int ia = __shfl(idxa, it, 64);
        int ib = __shfl(idxb, it, 64);
        half2v za = ((const half2v*)(z + (size_t)ia * N_CH))[lane];
        half2v zb = ((const half2v*)(z + (size_t)ib * N_CH))[lane];
        half2v s2;
        s2[0] = (_Float16)((float)za[0] * (float)zb[0]);
        s2[1] = (_Float16)((float)za[1] * (float)zb[1]);
        int p = w * 16 + it;
        sls2[p * 64 + (((lane >> 2) ^ (p & 15)) << 2) + (lane & 3)] = s2;
    }
    __syncthreads();
    // A-frags: row p = w*16 + m16 (p&15 == m16)
    half8 a[4];
    #pragma unroll
    for (int kk = 0; kk < 4; ++kk)
        a[kk] = sls[(w * 16 + m16) * 16 + ((kk * 4 + quad) ^ m16)];
    float rsum[4] = {0.f, 0.f, 0.f, 0.f};
    #pragma unroll
    for (int jt = 0; jt < 4; ++jt) {
        floatx4 acc = {0.f, 0.f, 0.f, 0.f};
        #pragma unroll
        for (int kk = 0; kk < 4; ++kk) {
            int r = jt * 16 + m16;
            half8 bfr = w1ls[r * 16 + ((kk * 4 + quad) ^ m16)];
            acc = __builtin_amdgcn_mfma_f32_16x16x32_f16(a[kk], bfr, acc, 0, 0, 0);
        }
        int j = jt * 16 + m16;
        float b1j = b1[j], w2j = w2[j];
        #pragma unroll
        for (int reg = 0; reg < 4; ++reg) {
            float v = fmaxf(acc[reg] + b1j, 0.f) * w2j;
            v += __shfl_xor(v, 1, 64);
            v += __shfl_xor(v, 2, 64);
            v += __shfl_xor(v, 4, 64);
            v += __shfl_xor(v, 8, 64);
            rsum[reg] += v;          // valid at m16==0 lanes
        }
    }
    if (m16 == 0) {
        float bb = b2[0];
        #pragma unroll
        for (int reg = 0; reg < 4; ++reg) {
            int gp = pbase + w * 16 + quad * 4 + reg;
            if (gp < m) out[gp] = rsum[reg] + bb;
        }
    }
}

// ---------------- launch ----------------

extern "C" void kernel_launch(void* const* d_in, const int* in_sizes, int n_in,
                              void* d_out, int out_size, void* d_ws, size_t ws_size,
                              hipStream_t stream) {
    const float* x   = (const float*)d_in[0];
    const int*   ei  = (const int*)d_in[1];
    const int*   eli = (const int*)d_in[2];
    const float* W   = (const float*)d_in[3];
    const float* bc  = (const float*)d_in[4];
    const float* W1  = (const float*)d_in[5];
    const float* b1  = (const float*)d_in[6];
    const float* w2  = (const float*)d_in[7];
    const float* b2  = (const float*)d_in[8];
    float* out = (float*)d_out;

    const int N = in_sizes[0] / N_CH;   // 50000
    const int E = in_sizes[1] / 2;      // 600000
    const int M = in_sizes[2] / 2;      // 200000

    const int* src = ei;
    const int* dst = ei + E;
    const int* ai  = eli;
    const int* bi  = eli + M;

    // workspace layout
    _Float16* hb0 = (_Float16*)d_ws;                 // N*128 halves (x16 -> hop2 out)
    _Float16* hb1 = hb0 + (size_t)N * N_CH;          // N*128 halves (hop1 out -> z)
    _Float16* wh  = hb1 + (size_t)N * N_CH;          // 16384
    _Float16* w1h = wh + 16384;                      // 8192
    int2*  csr2 = (int2*)(w1h + 8192);               // E int2
    int*   cnt  = (int*)(csr2 + E);                  // N
    int*   off  = cnt + N;                           // N
    int*   cur  = off + N;                           // N
    float* dnv  = (float*)(cur + N);                 // N
    int*   bsum = (int*)(dnv + N);                   // 64
    int*   bbas = bsum + 64;                         // 64

    // 1) CSR by dst; hierarchical scan; fp16 conversions
    int nb = (N + 1023) / 1024;
    k_zero<<<(N + 255) / 256, 256, 0, stream>>>(cnt, N);
    k_count<<<(E + 255) / 256, 256, 0, stream>>>(dst, cnt, E);
    k_scan1<<<nb, 1024, 0, stream>>>(cnt, off, bsum, N);
    k_scan2<<<1, 64, 0, stream>>>(bsum, bbas, nb);
    k_scan3<<<(N + 255) / 256, 256, 0, stream>>>(cnt, off, bbas, cur, dnv, N);
    k_fill<<<(E + 255) / 256, 256, 0, stream>>>(src, dst, cur, dnv, csr2, E);
    int nx4 = N * N_CH / 4, nw4 = N_CH * N_CH / 4, nw14 = 64 * N_CH / 4;
    int tot4 = nx4 + nw4 + nw14;
    k_cvt<<<(tot4 + 255) / 256, 256, 0, stream>>>(x, hb0, nx4, W, wh, nw4, W1, w1h, nw14);

    // 2) two propagation hops (fp16 rows, fp32 accumulate)
    int hop_blocks = (N + 3) / 4;
    k_hop16<<<hop_blocks, 256, 0, stream>>>(hb0, hb1, off, cnt, dnv, csr2, N);
    k_hop16<<<hop_blocks, 256, 0, stream>>>(hb1, hb0, off, cnt, dnv, csr2, N);

    // 3) z = h @ W^T + bc  (fp16 MFMA, into hb1)
    k_zlin_mfma<<<(N + 63) / 64, 256, 0, stream>>>(hb0, wh, bc, hb1, N);

    // 4) decode (fp16 MFMA, 64 pairs x 64 hidden per block)
    k_decode_mfma<<<(M + 63) / 64, 256, 0, stream>>>(hb1, ai, bi, w1h, b1, w2, b2, out, M);
}

// Round 6
// 233.683 us; speedup vs baseline: 2.0982x; 1.0924x over previous
//
#include <hip/hip_runtime.h>

#define N_CH 128   // IN_CH == OUT_CH == 128

typedef _Float16 half8  __attribute__((ext_vector_type(8)));
typedef _Float16 half4v __attribute__((ext_vector_type(4)));
typedef float    floatx4 __attribute__((ext_vector_type(4)));

// ---------------- CSR build ----------------

__global__ void k_zero(int* __restrict__ cnt, int n) {
    int i = blockIdx.x * blockDim.x + threadIdx.x;
    if (i < n) cnt[i] = 0;
}

__global__ void k_count(const int* __restrict__ dst, int* __restrict__ cnt, int E) {
    int e = blockIdx.x * blockDim.x + threadIdx.x;
    if (e < E) atomicAdd(&cnt[dst[e]], 1);
}

// hierarchical scan, pass 1: per-block (1024) local exclusive scan + block total
__global__ __launch_bounds__(1024) void k_scan1(const int* __restrict__ cnt,
                                                int* __restrict__ offs,
                                                int* __restrict__ bsum, int n) {
    __shared__ int ssum[16];
    int tid = threadIdx.x;
    int lane = tid & 63, wid = tid >> 6;
    int i = blockIdx.x * 1024 + tid;
    int v = (i < n) ? cnt[i] : 0;
    int x = v;
    #pragma unroll
    for (int off = 1; off < 64; off <<= 1) {
        int y = __shfl_up(x, off, 64);
        if (lane >= off) x += y;
    }
    if (lane == 63) ssum[wid] = x;
    __syncthreads();
    if (wid == 0 && lane < 16) {
        int s = ssum[lane];
        #pragma unroll
        for (int off = 1; off < 16; off <<= 1) {
            int y = __shfl_up(s, off, 64);
            if (lane >= off) s += y;
        }
        ssum[lane] = s;
    }
    __syncthreads();
    int waveoff = (wid > 0) ? ssum[wid - 1] : 0;
    int incl = x + waveoff;
    if (i < n) offs[i] = incl - v;          // local exclusive
    if (tid == 1023) bsum[blockIdx.x] = incl;
}

// pass 2: scan block sums (nb <= 64) -> exclusive bases
__global__ __launch_bounds__(64) void k_scan2(const int* __restrict__ bsum,
                                              int* __restrict__ bbase, int nb) {
    int lane = threadIdx.x;
    int v = (lane < nb) ? bsum[lane] : 0;
    int x = v;
    #pragma unroll
    for (int off = 1; off < 64; off <<= 1) {
        int y = __shfl_up(x, off, 64);
        if (lane >= off) x += y;
    }
    if (lane < nb) bbase[lane] = x - v;
}

// pass 3: add base, replicate to cur, compute dinv
__global__ void k_scan3(const int* __restrict__ cnt, int* __restrict__ offs,
                        const int* __restrict__ bbase, int* __restrict__ cur,
                        float* __restrict__ dinv, int n) {
    int i = blockIdx.x * blockDim.x + threadIdx.x;
    if (i < n) {
        int o = offs[i] + bbase[i >> 10];
        offs[i] = o;
        cur[i]  = o;
        dinv[i] = rsqrtf((float)(cnt[i] + 1));   // deg includes self-loop
    }
}

// fill: src index only (weights folded into pre-scaled rows)
__global__ void k_fill(const int* __restrict__ src, const int* __restrict__ dst,
                       int* __restrict__ cur, int* __restrict__ csr, int E) {
    int e = blockIdx.x * blockDim.x + threadIdx.x;
    if (e < E) {
        int p = atomicAdd(&cur[dst[e]], 1);
        csr[p] = src[e];
    }
}

// ---------------- conversions ----------------
// u0 = fp16(dinv[i] * x[i][:]); W, W1 -> fp16; zero row N of both hop buffers.

__global__ void k_cvt(const float* __restrict__ x, const float* __restrict__ dinv,
                      _Float16* __restrict__ u0, _Float16* __restrict__ u1,
                      const float* __restrict__ W,  _Float16* __restrict__ wh,
                      const float* __restrict__ W1, _Float16* __restrict__ w1h,
                      int n) {
    int nx4  = n * (N_CH / 4);
    int nw4  = N_CH * N_CH / 4;
    int nw14 = 64 * N_CH / 4;
    int i = blockIdx.x * blockDim.x + threadIdx.x;
    if (i < nx4) {
        float d = dinv[i >> 5];
        float4 v = ((const float4*)x)[i];
        half4v o;
        o[0] = (_Float16)(d * v.x); o[1] = (_Float16)(d * v.y);
        o[2] = (_Float16)(d * v.z); o[3] = (_Float16)(d * v.w);
        ((half4v*)u0)[i] = o;
        return;
    }
    int j = i - nx4;
    if (j < nw4) {
        float4 v = ((const float4*)W)[j];
        half4v o;
        o[0] = (_Float16)v.x; o[1] = (_Float16)v.y; o[2] = (_Float16)v.z; o[3] = (_Float16)v.w;
        ((half4v*)wh)[j] = o;
        return;
    }
    j -= nw4;
    if (j < nw14) {
        float4 v = ((const float4*)W1)[j];
        half4v o;
        o[0] = (_Float16)v.x; o[1] = (_Float16)v.y; o[2] = (_Float16)v.z; o[3] = (_Float16)v.w;
        ((half4v*)w1h)[j] = o;
        return;
    }
    j -= nw14;
    if (j < 64) {   // zero row n of u0 (32 granules) and u1 (32 granules)
        half4v zz; zz[0] = (_Float16)0.f; zz[1] = (_Float16)0.f; zz[2] = (_Float16)0.f; zz[3] = (_Float16)0.f;
        _Float16* dst16 = (j < 32) ? u0 : u1;
        ((half4v*)(dst16 + (size_t)n * N_CH))[j & 31] = zz;
    }
}

// ---------------- one hop: out[i] = scale_i * ( u[i] + sum_s u[s] ) ----------------
// 16-lane group per node (4 nodes/wave, 16/block); lane&15 = 16B chunk of row.
// 8 neighbor rows in flight per group; tail clamps to zero row (index n).

__global__ __launch_bounds__(256) void k_hop16(const _Float16* __restrict__ hin,
                                               _Float16* __restrict__ hout,
                                               const int* __restrict__ offs,
                                               const int* __restrict__ cnt,
                                               const float* __restrict__ dinv,
                                               const int* __restrict__ csr,
                                               int n, int squared) {
    int tid  = threadIdx.x;
    int node = blockIdx.x * 16 + (tid >> 4);
    int c16  = tid & 15;
    if (node >= n) return;
    float di = dinv[node];
    float sc = squared ? di * di : di;
    int s0 = offs[node], c = cnt[node];
    const int* lst = csr + s0;
    half8 self = ((const half8*)(hin + (size_t)node * N_CH))[c16];
    float acc[8];
    #pragma unroll
    for (int j = 0; j < 8; ++j) acc[j] = (float)self[j];
    for (int t0 = 0; t0 < c; t0 += 8) {
        int idx[8];
        #pragma unroll
        for (int i = 0; i < 8; ++i) {
            int t = t0 + i;
            int v = lst[t];                 // overread safe: csr followed by ws arrays
            idx[i] = (t < c) ? v : n;       // zero row for tail
        }
        half8 u[8];
        #pragma unroll
        for (int i = 0; i < 8; ++i)
            u[i] = ((const half8*)(hin + (size_t)idx[i] * N_CH))[c16];
        #pragma unroll
        for (int i = 0; i < 8; ++i)
            #pragma unroll
            for (int j = 0; j < 8; ++j) acc[j] += (float)u[i][j];
    }
    half8 o;
    #pragma unroll
    for (int j = 0; j < 8; ++j) o[j] = (_Float16)(sc * acc[j]);
    ((half8*)(hout + (size_t)node * N_CH))[c16] = o;
}

// ---------------- z = h @ W^T + b : fp16 MFMA GEMM ----------------
// block = 4 waves, tile 64 nodes x 128 out-ch. W (128x128 fp16) in swizzled LDS.
// mfma_f32_16x16x32_f16: A[m=lane&15][k=quad*8+j], B[n=lane&15][k=quad*8+j],
// D: col=lane&15, row=quad*4+reg.

__global__ __launch_bounds__(256) void k_zlin_mfma(const _Float16* __restrict__ h,
                                                   const _Float16* __restrict__ wh,
                                                   const float* __restrict__ bc,
                                                   _Float16* __restrict__ z, int n) {
    __shared__ half8 wls[128 * 16];   // row r chunk c at r*16 + (c^(r&15))
    int tid = threadIdx.x;
    int lane = tid & 63, w = tid >> 6;
    int quad = lane >> 4, m16 = lane & 15;
    int nb = blockIdx.x * 64;
    #pragma unroll
    for (int i = 0; i < 8; ++i) {
        int g = tid + 256 * i;   // 0..2047 chunk id = r*16 + c
        int r = g >> 4, c = g & 15;
        wls[r * 16 + (c ^ (r & 15))] = ((const half8*)wh)[g];
    }
    // preload A-frags: node row = nb + w*16 + m16, chunk = kk*4 + quad
    int arow = nb + w * 16 + m16;      // may run past n; stays inside d_ws
    const half8* hrow = (const half8*)(h + (size_t)arow * N_CH);
    half8 a[4];
    #pragma unroll
    for (int kk = 0; kk < 4; ++kk) a[kk] = hrow[kk * 4 + quad];
    __syncthreads();
    int outnode0 = nb + w * 16 + quad * 4;
    #pragma unroll
    for (int jt = 0; jt < 8; ++jt) {
        floatx4 acc = {0.f, 0.f, 0.f, 0.f};
        #pragma unroll
        for (int kk = 0; kk < 4; ++kk) {
            int r = jt * 16 + m16;
            half8 bfr = wls[r * 16 + ((kk * 4 + quad) ^ m16)];
            acc = __builtin_amdgcn_mfma_f32_16x16x32_f16(a[kk], bfr, acc, 0, 0, 0);
        }
        int j = jt * 16 + m16;
        float bias = bc[j];
        #pragma unroll
        for (int reg = 0; reg < 4; ++reg) {
            int node = outnode0 + reg;
            if (node < n) z[(size_t)node * N_CH + j] = (_Float16)(acc[reg] + bias);
        }
    }
}

// ---------------- decode: fp16 MFMA, 64 pairs x 64 hidden per block ----------------
// staging 16B/lane: 4 pairs per wave-instr; W1 LDS-resident;
// epilogue: +b1, relu, *w2, shuffle-reduce over hidden, +b2.

__global__ __launch_bounds__(256) void k_decode_mfma(const _Float16* __restrict__ z,
        const int* __restrict__ ai, const int* __restrict__ bi,
        const _Float16* __restrict__ w1h, const float* __restrict__ b1,
        const float* __restrict__ w2, const float* __restrict__ b2,
        float* __restrict__ out, int m) {
    __shared__ half8 w1ls[64 * 16];
    __shared__ half8 sls[64 * 16];
    int tid = threadIdx.x;
    int lane = tid & 63, w = tid >> 6;
    int quad = lane >> 4, m16 = lane & 15;
    int pbase = blockIdx.x * 64;
    #pragma unroll
    for (int i = 0; i < 4; ++i) {
        int g = tid + 256 * i;   // 0..1023
        int r = g >> 4, c = g & 15;
        w1ls[r * 16 + (c ^ (r & 15))] = ((const half8*)w1h)[g];
    }
    // pair indices: lane holds pair (w*16 + (lane&15))
    int pidx = pbase + w * 16 + m16;
    if (pidx >= m) pidx = m - 1;
    int idxa = ai[pidx];
    int idxb = bi[pidx];
    // staging: 4 iterations x 4 pairs; lane&15 = chunk, lane>>4 = pair-in-group
    #pragma unroll
    for (int it = 0; it < 4; ++it) {
        int p = it * 4 + quad;             // pair within wave's 16
        int ia = __shfl(idxa, p, 64);
        int ib = __shfl(idxb, p, 64);
        half8 za = ((const half8*)(z + (size_t)ia * N_CH))[m16];
        half8 zb = ((const half8*)(z + (size_t)ib * N_CH))[m16];
        half8 s8 = za * zb;                // v_pk_mul_f16
        int pp = w * 16 + p;
        sls[pp * 16 + (m16 ^ (pp & 15))] = s8;
    }
    __syncthreads();
    // A-frags: row p = w*16 + m16 (p&15 == m16)
    half8 a[4];
    #pragma unroll
    for (int kk = 0; kk < 4; ++kk)
        a[kk] = sls[(w * 16 + m16) * 16 + ((kk * 4 + quad) ^ m16)];
    float rsum[4] = {0.f, 0.f, 0.f, 0.f};
    #pragma unroll
    for (int jt = 0; jt < 4; ++jt) {
        floatx4 acc = {0.f, 0.f, 0.f, 0.f};
        #pragma unroll
        for (int kk = 0; kk < 4; ++kk) {
            int r = jt * 16 + m16;
            half8 bfr = w1ls[r * 16 + ((kk * 4 + quad) ^ m16)];
            acc = __builtin_amdgcn_mfma_f32_16x16x32_f16(a[kk], bfr, acc, 0, 0, 0);
        }
        int j = jt * 16 + m16;
        float b1j = b1[j], w2j = w2[j];
        #pragma unroll
        for (int reg = 0; reg < 4; ++reg) {
            float v = fmaxf(acc[reg] + b1j, 0.f) * w2j;
            v += __shfl_xor(v, 1, 64);
            v += __shfl_xor(v, 2, 64);
            v += __shfl_xor(v, 4, 64);
            v += __shfl_xor(v, 8, 64);
            rsum[reg] += v;          // valid at m16==0 lanes
        }
    }
    if (m16 == 0) {
        float bb = b2[0];
        #pragma unroll
        for (int reg = 0; reg < 4; ++reg) {
            int gp = pbase + w * 16 + quad * 4 + reg;
            if (gp < m) out[gp] = rsum[reg] + bb;
        }
    }
}

// ---------------- launch ----------------

extern "C" void kernel_launch(void* const* d_in, const int* in_sizes, int n_in,
                              void* d_out, int out_size, void* d_ws, size_t ws_size,
                              hipStream_t stream) {
    const float* x   = (const float*)d_in[0];
    const int*   ei  = (const int*)d_in[1];
    const int*   eli = (const int*)d_in[2];
    const float* W   = (const float*)d_in[3];
    const float* bc  = (const float*)d_in[4];
    const float* W1  = (const float*)d_in[5];
    const float* b1  = (const float*)d_in[6];
    const float* w2  = (const float*)d_in[7];
    const float* b2  = (const float*)d_in[8];
    float* out = (float*)d_out;

    const int N = in_sizes[0] / N_CH;   // 50000
    const int E = in_sizes[1] / 2;      // 600000
    const int M = in_sizes[2] / 2;      // 200000

    const int* src = ei;
    const int* dst = ei + E;
    const int* ai  = eli;
    const int* bi  = eli + M;

    // workspace layout: two (N+1)-row fp16 buffers (row N = zero row)
    _Float16* hb0 = (_Float16*)d_ws;                       // (N+1)*128
    _Float16* hb1 = hb0 + (size_t)(N + 1) * N_CH;          // (N+1)*128
    _Float16* wh  = hb1 + (size_t)(N + 1) * N_CH;          // 16384
    _Float16* w1h = wh + 16384;                            // 8192
    int*   csr  = (int*)(w1h + 8192);                      // E
    int*   cnt  = csr + E;                                 // N
    int*   off  = cnt + N;                                 // N
    int*   cur  = off + N;                                 // N
    float* dnv  = (float*)(cur + N);                       // N
    int*   bsum = (int*)(dnv + N);                         // 64
    int*   bbas = bsum + 64;                               // 64

    // 1) CSR by dst; hierarchical scan; fp16 conversions (u0 = dinv*x)
    int nb = (N + 1023) / 1024;
    k_zero<<<(N + 255) / 256, 256, 0, stream>>>(cnt, N);
    k_count<<<(E + 255) / 256, 256, 0, stream>>>(dst, cnt, E);
    k_scan1<<<nb, 1024, 0, stream>>>(cnt, off, bsum, N);
    k_scan2<<<1, 64, 0, stream>>>(bsum, bbas, nb);
    k_scan3<<<(N + 255) / 256, 256, 0, stream>>>(cnt, off, bbas, cur, dnv, N);
    k_fill<<<(E + 255) / 256, 256, 0, stream>>>(src, dst, cur, csr, E);
    int tot4 = N * (N_CH / 4) + N_CH * N_CH / 4 + 64 * N_CH / 4 + 64;
    k_cvt<<<(tot4 + 255) / 256, 256, 0, stream>>>(x, dnv, hb0, hb1, W, wh, W1, w1h, N);

    // 2) two hops: u1 = dinv^2*(u0_i + sum u0_s); h2 = dinv*(u1_i + sum u1_s)
    int hop_blocks = (N + 15) / 16;
    k_hop16<<<hop_blocks, 256, 0, stream>>>(hb0, hb1, off, cnt, dnv, csr, N, 1);
    k_hop16<<<hop_blocks, 256, 0, stream>>>(hb1, hb0, off, cnt, dnv, csr, N, 0);

    // 3) z = h2 @ W^T + bc  (fp16 MFMA, into hb1)
    k_zlin_mfma<<<(N + 63) / 64, 256, 0, stream>>>(hb0, wh, bc, hb1, N);

    // 4) decode (fp16 MFMA, 64 pairs x 64 hidden per block)
    k_decode_mfma<<<(M + 63) / 64, 256, 0, stream>>>(hb1, ai, bi, w1h, b1, w2, b2, out, M);
}